// Round 1
// 242.628 us; speedup vs baseline: 1.1824x; 1.1824x over previous
//
#include <hip/hip_runtime.h>
#include <hip/hip_fp16.h>
#include <math.h>

#define FACE_W 256
#define CH 32
#define BATCH 2
#define OUT_H (2 * FACE_W)            // 512
#define OUT_W (4 * FACE_W)            // 1024
#define N_PIX (OUT_H * OUT_W)         // 524288 = 2^19
#define PLANE (FACE_W * FACE_W)       // 65536
#define FACE_STRIDE (CH * PLANE)      // 2^21 floats
#define BATCH_STRIDE (6 * FACE_STRIDE)
#define OUT_PLANE (OUT_H * OUT_W)

// fp16 intermediate: (b, f, pixel, ch) halfs.  48 MiB.
#define TRANS_H_ELEMS ((size_t)BATCH * 6 * PLANE * CH)
#define TRANS_H_BYTES (TRANS_H_ELEMS * 2)            // 48 MiB
#define REC_BYTES     ((size_t)N_PIX * 8)            // 4 MiB (uint2 records)

#define TPOSE_BLOCKS (BATCH * 6 * (PLANE / 64))      // 12288
#define GRID_BLOCKS  (N_PIX / 256)                   // 2048

__device__ __forceinline__ float2 h2f2(unsigned u) {
    union { unsigned u; __half2 h; } c;
    c.u = u;
    return __half22float2(c.h);
}

// ---------------- Kernel A: transpose->fp16 + grid math, fused --------------
// Blocks [0, TPOSE_BLOCKS): transpose (b,f,C,W,W) f32 -> (b,f,W,W,C) f16.
// Blocks [TPOSE_BLOCKS, +GRID_BLOCKS): per-pixel fp64 grid math -> 8 B record.
// The VALU-bound fp64 blocks overlap with the BW-bound transpose blocks.
__global__ __launch_bounds__(256) void prep_kernel(
    const float* __restrict__ in, ushort* __restrict__ out_h,
    uint2* __restrict__ rec) {
    if (blockIdx.x < TPOSE_BLOCKS) {
        // ---- transpose path: 64 pixels x 32 channels per block ----
        __shared__ ushort tile[64][CH + 2];      // stride 34 ushorts: conflict-free
        int bf  = blockIdx.x >> 10;              // (b*6+face) in [0,12)
        int p0  = (blockIdx.x & 1023) << 6;      // pixel tile base
        int tid = threadIdx.x;

        const float* src = in + (size_t)bf * FACE_STRIDE + p0;
        int pl = tid & 63, c0 = tid >> 6;        // read: lanes sweep pixels (256B/instr)
        #pragma unroll
        for (int c = c0; c < CH; c += 4)
            tile[pl][c] = __half_as_ushort(__float2half(src[(size_t)c * PLANE + pl]));
        __syncthreads();

        // write: each lane emits a ushort2 (2 ch); wave covers 256 B contiguous
        unsigned* dst = (unsigned*)(out_h + ((size_t)bf * PLANE + p0) * CH);
        int cl = tid & 15, pl2 = tid >> 4;
        #pragma unroll
        for (int k = 0; k < 4; ++k) {
            int p = pl2 + 16 * k;
            dst[p * (CH / 2) + cl] = *(const unsigned*)&tile[p][2 * cl];
        }
    } else {
        // ---- grid path: fp64 keeps the face decision far from cube-edge
        // boundaries (round-1 verified: absmax 0.0156 vs threshold 0.096) ----
        int pix = (blockIdx.x - TPOSE_BLOCKS) * 256 + threadIdx.x;
        int xx = pix & (OUT_W - 1);
        int yy = pix >> 10;

        const double PI = 3.14159265358979323846;
        double theta = (2.0 * (xx + 0.5) / OUT_W - 1.0) * PI;
        double phi   = (2.0 * (yy + 0.5) / OUT_H - 1.0) * (PI * 0.5);
        double cph = cos(phi);
        double sx = cph * cos(theta);
        double sy = cph * sin(theta);
        double sz = sin(phi);
        double ax = fabs(sx), ay = fabs(sy), az = fabs(sz);

        const double EPS = 1e-9;
        int face;
        double u, v;
        if (ax >= ay && ax >= az) {
            face = (sx >= 0.0) ? 0 : 1;
            double d = fmax(ax, EPS);
            u = ((face == 0) ? sy : -sy) / d;
            v = sz / d;
        } else if (ay >= az) {
            face = (sy >= 0.0) ? 2 : 3;
            double d = fmax(ay, EPS);
            u = ((face == 2) ? -sx : sx) / d;
            v = sz / d;
        } else {
            face = (sz >= 0.0) ? 4 : 5;
            double d = fmax(az, EPS);
            u = sy / d;
            v = ((face == 4) ? -sx : sx) / d;
        }

        float px = (float)((u + 1.0) * 0.5 * (FACE_W - 1));
        float py = (float)((v + 1.0) * 0.5 * (FACE_W - 1));
        float fx0 = floorf(px), fy0 = floorf(py);
        float wx = px - fx0, wy = py - fy0;
        int x0 = min(max((int)fx0, 0), FACE_W - 1);
        int y0 = min(max((int)fy0, 0), FACE_W - 1);

        unsigned off00 = ((unsigned)face << 16) | (unsigned)(y0 * FACE_W + x0);
        unsigned wpack = (unsigned)__half_as_ushort(__float2half(wx)) |
                         ((unsigned)__half_as_ushort(__float2half(wy)) << 16);
        rec[pix] = make_uint2(off00, wpack);
    }
}

// ---------------- Kernel B: gather+blend on channel-last fp16 data ----------
// 4 lanes per pixel; each lane owns 8 consecutive channels -> every corner
// gather is a 16 B contiguous uint4 per lane (64 B/pixel/corner).  Both
// batches handled by the same thread: one rec load + one address calc feeds
// 8 in-flight gathers.  Output stores: 4 planes x 64 B contiguous per instr.
__global__ __launch_bounds__(256) void sample_h_kernel(
    const ushort* __restrict__ in_h, const uint2* __restrict__ rec,
    float* __restrict__ out) {
    unsigned g = blockIdx.x * blockDim.x + threadIdx.x;
    int cg  = g & 3;                 // channel group (8 ch each)
    int pix = g >> 2;

    uint2 r = rec[pix];
    int face  = r.x >> 16;
    int pix16 = r.x & 0xFFFF;
    int x0 = r.x & 255;
    int y0 = (r.x >> 8) & 255;
    float wx = __half2float(__ushort_as_half((ushort)(r.y & 0xFFFF)));
    float wy = __half2float(__ushort_as_half((ushort)(r.y >> 16)));
    int dxE = (x0 < FACE_W - 1) ? CH : 0;              // +1 in x -> +32 halfs
    int dyE = (y0 < FACE_W - 1) ? FACE_W * CH : 0;     // +1 in y -> +8192 halfs

    float w00 = (1.0f - wx) * (1.0f - wy);
    float w10 = wx * (1.0f - wy);
    float w01 = (1.0f - wx) * wy;
    float w11 = wx * wy;

    const ushort* s0 = in_h + ((size_t)face * PLANE + pix16) * CH + cg * 8;

    #pragma unroll
    for (int b = 0; b < BATCH; ++b) {
        const ushort* sb = s0 + (size_t)b * (6 * (size_t)PLANE * CH);
        uint4 q00 = *(const uint4*)(sb);
        uint4 q10 = *(const uint4*)(sb + dxE);
        uint4 q01 = *(const uint4*)(sb + dyE);
        uint4 q11 = *(const uint4*)(sb + dxE + dyE);

        float* ob = out + ((size_t)(b * CH + cg * 8)) * OUT_PLANE + pix;
        #pragma unroll
        for (int j = 0; j < 4; ++j) {
            float2 f00 = h2f2(((const unsigned*)&q00)[j]);
            float2 f10 = h2f2(((const unsigned*)&q10)[j]);
            float2 f01 = h2f2(((const unsigned*)&q01)[j]);
            float2 f11 = h2f2(((const unsigned*)&q11)[j]);
            ob[(size_t)(2 * j) * OUT_PLANE] =
                f00.x * w00 + f10.x * w10 + f01.x * w01 + f11.x * w11;
            ob[(size_t)(2 * j + 1) * OUT_PLANE] =
                f00.y * w00 + f10.y * w10 + f01.y * w01 + f11.y * w11;
        }
    }
}

// ---------------- Fallback: fully fused (tiny workspace) --------------------
__global__ __launch_bounds__(256) void cube2equi_fused(
    const float* __restrict__ in, float* __restrict__ out) {
    int pix = blockIdx.x * blockDim.x + threadIdx.x;
    if (pix >= N_PIX) return;
    int xx = pix & (OUT_W - 1);
    int yy = pix >> 10;

    const double PI = 3.14159265358979323846;
    double theta = (2.0 * (xx + 0.5) / OUT_W - 1.0) * PI;
    double phi   = (2.0 * (yy + 0.5) / OUT_H - 1.0) * (PI * 0.5);
    double cph = cos(phi);
    double sx = cph * cos(theta);
    double sy = cph * sin(theta);
    double sz = sin(phi);
    double ax = fabs(sx), ay = fabs(sy), az = fabs(sz);

    const double EPS = 1e-9;
    int face;
    double u, v;
    if (ax >= ay && ax >= az) {
        face = (sx >= 0.0) ? 0 : 1;
        double d = fmax(ax, EPS);
        u = ((face == 0) ? sy : -sy) / d;
        v = sz / d;
    } else if (ay >= az) {
        face = (sy >= 0.0) ? 2 : 3;
        double d = fmax(ay, EPS);
        u = ((face == 2) ? -sx : sx) / d;
        v = sz / d;
    } else {
        face = (sz >= 0.0) ? 4 : 5;
        double d = fmax(az, EPS);
        u = sy / d;
        v = ((face == 4) ? -sx : sx) / d;
    }

    float px = (float)((u + 1.0) * 0.5 * (FACE_W - 1));
    float py = (float)((v + 1.0) * 0.5 * (FACE_W - 1));
    float fx0 = floorf(px), fy0 = floorf(py);
    float wx = px - fx0, wy = py - fy0;
    int x0 = min(max((int)fx0, 0), FACE_W - 1);
    int x1 = min(max((int)fx0 + 1, 0), FACE_W - 1);
    int y0 = min(max((int)fy0, 0), FACE_W - 1);
    int y1 = min(max((int)fy0 + 1, 0), FACE_W - 1);

    float w00 = (1.0f - wx) * (1.0f - wy);
    float w10 = wx * (1.0f - wy);
    float w01 = (1.0f - wx) * wy;
    float w11 = wx * wy;

    int o00 = y0 * FACE_W + x0;
    int o10 = y0 * FACE_W + x1;
    int o01 = y1 * FACE_W + x0;
    int o11 = y1 * FACE_W + x1;

    const float* fbase = in + (size_t)face * FACE_STRIDE;

    for (int b = 0; b < BATCH; ++b) {
        const float* bb = fbase + (size_t)b * BATCH_STRIDE;
        float* obp = out + (size_t)b * CH * OUT_PLANE + pix;
        #pragma unroll 4
        for (int c = 0; c < CH; ++c) {
            const float* p = bb + (size_t)c * PLANE;
            obp[(size_t)c * OUT_PLANE] = p[o00] * w00 + p[o10] * w10 +
                                         p[o01] * w01 + p[o11] * w11;
        }
    }
}

extern "C" void kernel_launch(void* const* d_in, const int* in_sizes, int n_in,
                              void* d_out, int out_size, void* d_ws, size_t ws_size,
                              hipStream_t stream) {
    const float* in = (const float*)d_in[0];
    float* out = (float*)d_out;

    if (ws_size >= TRANS_H_BYTES + REC_BYTES) {
        ushort* in_h = (ushort*)d_ws;
        uint2* rec = (uint2*)((char*)d_ws + TRANS_H_BYTES);
        prep_kernel<<<TPOSE_BLOCKS + GRID_BLOCKS, 256, 0, stream>>>(in, in_h, rec);
        // 4 lanes per pixel, both batches per thread: N_PIX*4 threads
        sample_h_kernel<<<(N_PIX * 4) / 256, 256, 0, stream>>>(in_h, rec, out);
    } else {
        cube2equi_fused<<<N_PIX / 256, 256, 0, stream>>>(in, out);
    }
}

// Round 2
// 230.546 us; speedup vs baseline: 1.2444x; 1.0524x over previous
//
#include <hip/hip_runtime.h>
#include <hip/hip_fp16.h>
#include <math.h>

#define FACE_W 256
#define CH 32
#define BATCH 2
#define OUT_H (2 * FACE_W)            // 512
#define OUT_W (4 * FACE_W)            // 1024
#define N_PIX (OUT_H * OUT_W)         // 524288 = 2^19
#define PLANE (FACE_W * FACE_W)       // 65536
#define FACE_STRIDE (CH * PLANE)      // 2^21 floats
#define BATCH_STRIDE (6 * FACE_STRIDE)
#define OUT_PLANE (OUT_H * OUT_W)

// fp16 intermediate: (b, f, pixel, ch) halfs.  48 MiB.
#define TRANS_H_ELEMS ((size_t)BATCH * 6 * PLANE * CH)
#define TRANS_H_BYTES (TRANS_H_ELEMS * 2)            // 48 MiB
#define REC_BYTES     ((size_t)N_PIX * 8)            // 4 MiB (uint2 records)

// transpose: 256 pixels x 32 ch per block -> PLANE/256 = 256 blocks per (b,f)
#define TPOSE_BLOCKS (BATCH * 6 * (PLANE / 256))     // 3072
#define GRID_BLOCKS  (N_PIX / 256)                   // 2048
#define SAMPLE_BLOCKS ((N_PIX * 4) / 256)            // 8192

// ext-vector types so __builtin_nontemporal_* lowers cleanly
typedef float  f4  __attribute__((ext_vector_type(4)));
typedef unsigned u4v __attribute__((ext_vector_type(4)));

__device__ __forceinline__ float2 h2f2(unsigned u) {
    union { unsigned u; __half2 h; } c;
    c.u = u;
    return __half22float2(c.h);
}
__device__ __forceinline__ unsigned packh2(float a, float b) {
    union { __half2 h; unsigned u; } c;
    c.h = __halves2half2(__float2half(a), __float2half(b));
    return c.u;
}

// ---------------- Kernel A: transpose->fp16 + grid math, fused --------------
// Blocks [0, TPOSE_BLOCKS): transpose (b,f,C,W,W) f32 -> (b,f,W,W,C) f16.
//   Global loads: float4 nontemporal (input is single-use; keep LLC for in_h).
//   Global stores: dwordx4, 64 B/pixel fully contiguous per wave.
//   LDS: stride 34 ushorts; read phase is dword-granular at dword-stride 17
//   -> bank = 17p mod 32 bijective, conflict-free.
// Blocks [TPOSE_BLOCKS, +GRID_BLOCKS): per-pixel fp64 grid math -> 8 B record
//   (fp64 keeps face decisions off cube-edge boundaries; verified absmax
//   0.03125 vs threshold 0.096).
__global__ __launch_bounds__(256) void prep_kernel(
    const float* __restrict__ in, ushort* __restrict__ out_h,
    uint2* __restrict__ rec) {
    if (blockIdx.x < TPOSE_BLOCKS) {
        __shared__ ushort tile[256][CH + 2];     // stride 34 ushorts = 68 B
        int bf  = blockIdx.x >> 8;               // (b*6+face) in [0,12)
        int p0  = (blockIdx.x & 255) << 8;       // 256-pixel tile base
        int tid = threadIdx.x;
        int l = tid & 63, w = tid >> 6;          // lane, wave

        const float* src = in + (size_t)bf * FACE_STRIDE + p0 + 4 * l;
        // Each thread: 4 channel-pairs, 4 consecutive pixels each.
        // Issue all 8 float4 loads up front (independent, hide latency).
        f4 A[4], B[4];
        #pragma unroll
        for (int it = 0; it < 4; ++it) {
            int cp = it * 4 + w;                 // channel pair 0..15
            A[it] = __builtin_nontemporal_load(
                        (const f4*)(src + (size_t)(2 * cp) * PLANE));
            B[it] = __builtin_nontemporal_load(
                        (const f4*)(src + (size_t)(2 * cp + 1) * PLANE));
        }
        #pragma unroll
        for (int it = 0; it < 4; ++it) {
            int cp = it * 4 + w;
            #pragma unroll
            for (int i = 0; i < 4; ++i)
                *(unsigned*)&tile[4 * l + i][2 * cp] = packh2(A[it][i], B[it][i]);
        }
        __syncthreads();

        // store: thread tid owns pixel p0+tid (64 B channel-last, contiguous)
        const ushort* row = tile[tid];
        uint4* dst = (uint4*)(out_h + ((size_t)bf * PLANE + p0 + tid) * CH);
        #pragma unroll
        for (int q = 0; q < 4; ++q) {
            unsigned u0 = *(const unsigned*)&row[8 * q + 0];
            unsigned u1 = *(const unsigned*)&row[8 * q + 2];
            unsigned u2 = *(const unsigned*)&row[8 * q + 4];
            unsigned u3 = *(const unsigned*)&row[8 * q + 6];
            dst[q] = make_uint4(u0, u1, u2, u3);
        }
    } else {
        int pix = (blockIdx.x - TPOSE_BLOCKS) * 256 + threadIdx.x;
        int xx = pix & (OUT_W - 1);
        int yy = pix >> 10;

        const double PI = 3.14159265358979323846;
        double theta = (2.0 * (xx + 0.5) / OUT_W - 1.0) * PI;
        double phi   = (2.0 * (yy + 0.5) / OUT_H - 1.0) * (PI * 0.5);
        double cph = cos(phi);
        double sx = cph * cos(theta);
        double sy = cph * sin(theta);
        double sz = sin(phi);
        double ax = fabs(sx), ay = fabs(sy), az = fabs(sz);

        const double EPS = 1e-9;
        int face;
        double u, v;
        if (ax >= ay && ax >= az) {
            face = (sx >= 0.0) ? 0 : 1;
            double d = fmax(ax, EPS);
            u = ((face == 0) ? sy : -sy) / d;
            v = sz / d;
        } else if (ay >= az) {
            face = (sy >= 0.0) ? 2 : 3;
            double d = fmax(ay, EPS);
            u = ((face == 2) ? -sx : sx) / d;
            v = sz / d;
        } else {
            face = (sz >= 0.0) ? 4 : 5;
            double d = fmax(az, EPS);
            u = sy / d;
            v = ((face == 4) ? -sx : sx) / d;
        }

        float px = (float)((u + 1.0) * 0.5 * (FACE_W - 1));
        float py = (float)((v + 1.0) * 0.5 * (FACE_W - 1));
        float fx0 = floorf(px), fy0 = floorf(py);
        float wx = px - fx0, wy = py - fy0;
        int x0 = min(max((int)fx0, 0), FACE_W - 1);
        int y0 = min(max((int)fy0, 0), FACE_W - 1);

        unsigned off00 = ((unsigned)face << 16) | (unsigned)(y0 * FACE_W + x0);
        unsigned wpack = (unsigned)__half_as_ushort(__float2half(wx)) |
                         ((unsigned)__half_as_ushort(__float2half(wy)) << 16);
        rec[pix] = make_uint2(off00, wpack);
    }
}

// ---------------- Kernel B: gather+blend on channel-last fp16 data ----------
// 4 lanes per pixel; each lane owns 8 consecutive channels -> every corner
// gather is a 16 B contiguous uint4; both batches per thread (one rec load +
// one address calc feeds 8 in-flight gathers).
// Output stores are NONTEMPORAL: 128 MiB of write-once data must not evict
// the 48 MiB in_h gather working set from L2/LLC.
// Bijective XCD-chunk swizzle: each XCD gets a contiguous output band, so
// the pole bands' face-4/5 working set (4 MiB) fits that XCD's private L2.
__global__ __launch_bounds__(256) void sample_h_kernel(
    const ushort* __restrict__ in_h, const uint2* __restrict__ rec,
    float* __restrict__ out) {
    unsigned bid = (blockIdx.x & 7) * (SAMPLE_BLOCKS / 8) + (blockIdx.x >> 3);
    unsigned g = bid * blockDim.x + threadIdx.x;
    int cg  = g & 3;                 // channel group (8 ch each)
    int pix = g >> 2;

    uint2 r = rec[pix];
    int face  = r.x >> 16;
    int pix16 = r.x & 0xFFFF;
    int x0 = r.x & 255;
    int y0 = (r.x >> 8) & 255;
    float wx = __half2float(__ushort_as_half((ushort)(r.y & 0xFFFF)));
    float wy = __half2float(__ushort_as_half((ushort)(r.y >> 16)));
    int dxE = (x0 < FACE_W - 1) ? CH : 0;              // +1 in x -> +32 halfs
    int dyE = (y0 < FACE_W - 1) ? FACE_W * CH : 0;     // +1 in y -> +8192 halfs

    float w00 = (1.0f - wx) * (1.0f - wy);
    float w10 = wx * (1.0f - wy);
    float w01 = (1.0f - wx) * wy;
    float w11 = wx * wy;

    const ushort* s0 = in_h + ((size_t)face * PLANE + pix16) * CH + cg * 8;

    #pragma unroll
    for (int b = 0; b < BATCH; ++b) {
        const ushort* sb = s0 + (size_t)b * (6 * (size_t)PLANE * CH);
        uint4 q00 = *(const uint4*)(sb);
        uint4 q10 = *(const uint4*)(sb + dxE);
        uint4 q01 = *(const uint4*)(sb + dyE);
        uint4 q11 = *(const uint4*)(sb + dxE + dyE);

        float* ob = out + ((size_t)(b * CH + cg * 8)) * OUT_PLANE + pix;
        #pragma unroll
        for (int j = 0; j < 4; ++j) {
            float2 f00 = h2f2(((const unsigned*)&q00)[j]);
            float2 f10 = h2f2(((const unsigned*)&q10)[j]);
            float2 f01 = h2f2(((const unsigned*)&q01)[j]);
            float2 f11 = h2f2(((const unsigned*)&q11)[j]);
            __builtin_nontemporal_store(
                f00.x * w00 + f10.x * w10 + f01.x * w01 + f11.x * w11,
                &ob[(size_t)(2 * j) * OUT_PLANE]);
            __builtin_nontemporal_store(
                f00.y * w00 + f10.y * w10 + f01.y * w01 + f11.y * w11,
                &ob[(size_t)(2 * j + 1) * OUT_PLANE]);
        }
    }
}

// ---------------- Fallback: fully fused (tiny workspace) --------------------
__global__ __launch_bounds__(256) void cube2equi_fused(
    const float* __restrict__ in, float* __restrict__ out) {
    int pix = blockIdx.x * blockDim.x + threadIdx.x;
    if (pix >= N_PIX) return;
    int xx = pix & (OUT_W - 1);
    int yy = pix >> 10;

    const double PI = 3.14159265358979323846;
    double theta = (2.0 * (xx + 0.5) / OUT_W - 1.0) * PI;
    double phi   = (2.0 * (yy + 0.5) / OUT_H - 1.0) * (PI * 0.5);
    double cph = cos(phi);
    double sx = cph * cos(theta);
    double sy = cph * sin(theta);
    double sz = sin(phi);
    double ax = fabs(sx), ay = fabs(sy), az = fabs(sz);

    const double EPS = 1e-9;
    int face;
    double u, v;
    if (ax >= ay && ax >= az) {
        face = (sx >= 0.0) ? 0 : 1;
        double d = fmax(ax, EPS);
        u = ((face == 0) ? sy : -sy) / d;
        v = sz / d;
    } else if (ay >= az) {
        face = (sy >= 0.0) ? 2 : 3;
        double d = fmax(ay, EPS);
        u = ((face == 2) ? -sx : sx) / d;
        v = sz / d;
    } else {
        face = (sz >= 0.0) ? 4 : 5;
        double d = fmax(az, EPS);
        u = sy / d;
        v = ((face == 4) ? -sx : sx) / d;
    }

    float px = (float)((u + 1.0) * 0.5 * (FACE_W - 1));
    float py = (float)((v + 1.0) * 0.5 * (FACE_W - 1));
    float fx0 = floorf(px), fy0 = floorf(py);
    float wx = px - fx0, wy = py - fy0;
    int x0 = min(max((int)fx0, 0), FACE_W - 1);
    int x1 = min(max((int)fx0 + 1, 0), FACE_W - 1);
    int y0 = min(max((int)fy0, 0), FACE_W - 1);
    int y1 = min(max((int)fy0 + 1, 0), FACE_W - 1);

    float w00 = (1.0f - wx) * (1.0f - wy);
    float w10 = wx * (1.0f - wy);
    float w01 = (1.0f - wx) * wy;
    float w11 = wx * wy;

    int o00 = y0 * FACE_W + x0;
    int o10 = y0 * FACE_W + x1;
    int o01 = y1 * FACE_W + x0;
    int o11 = y1 * FACE_W + x1;

    const float* fbase = in + (size_t)face * FACE_STRIDE;

    for (int b = 0; b < BATCH; ++b) {
        const float* bb = fbase + (size_t)b * BATCH_STRIDE;
        float* obp = out + (size_t)b * CH * OUT_PLANE + pix;
        #pragma unroll 4
        for (int c = 0; c < CH; ++c) {
            const float* p = bb + (size_t)c * PLANE;
            obp[(size_t)c * OUT_PLANE] = p[o00] * w00 + p[o10] * w10 +
                                         p[o01] * w01 + p[o11] * w11;
        }
    }
}

extern "C" void kernel_launch(void* const* d_in, const int* in_sizes, int n_in,
                              void* d_out, int out_size, void* d_ws, size_t ws_size,
                              hipStream_t stream) {
    const float* in = (const float*)d_in[0];
    float* out = (float*)d_out;

    if (ws_size >= TRANS_H_BYTES + REC_BYTES) {
        ushort* in_h = (ushort*)d_ws;
        uint2* rec = (uint2*)((char*)d_ws + TRANS_H_BYTES);
        prep_kernel<<<TPOSE_BLOCKS + GRID_BLOCKS, 256, 0, stream>>>(in, in_h, rec);
        sample_h_kernel<<<SAMPLE_BLOCKS, 256, 0, stream>>>(in_h, rec, out);
    } else {
        cube2equi_fused<<<N_PIX / 256, 256, 0, stream>>>(in, out);
    }
}